// Round 1
// baseline (1278.341 us; speedup 1.0000x reference)
//
#include <hip/hip_runtime.h>
#include <math.h>

typedef unsigned short u16;
typedef u16 u16x8 __attribute__((ext_vector_type(8)));
typedef __bf16 bf16x8 __attribute__((ext_vector_type(8)));
typedef float f32x4 __attribute__((ext_vector_type(4)));

__device__ __forceinline__ u16 f2bf(float f) {
    union { float f; unsigned u; } v; v.f = f;
    unsigned r = v.u + 0x7fffu + ((v.u >> 16) & 1u);
    return (u16)(r >> 16);
}

// ---------------- NCHW -> NHWC transpose (fp32) ----------------
__global__ __launch_bounds__(256) void transpose_in(const float* __restrict__ in,
                                                    float* __restrict__ out) {
    __shared__ float t[32][33];
    const int b = blockIdx.z;
    const int c0 = blockIdx.y * 32;
    const int s0 = blockIdx.x * 32;
    const int tx = threadIdx.x, ty = threadIdx.y; // 32 x 8
    const float* src = in + (size_t)b * 192 * 65536;
    float* dst = out + (size_t)b * 65536 * 192;
#pragma unroll
    for (int k = 0; k < 4; k++)
        t[ty + k * 8][tx] = src[(size_t)(c0 + ty + k * 8) * 65536 + s0 + tx];
    __syncthreads();
#pragma unroll
    for (int k = 0; k < 4; k++)
        dst[(size_t)(s0 + ty + k * 8) * 192 + c0 + tx] = t[tx][ty + k * 8];
}

// ---------------- NHWC -> NCHW transpose (fp32) ----------------
__global__ __launch_bounds__(256) void transpose_out(const float* __restrict__ in,
                                                     float* __restrict__ out) {
    __shared__ float t[32][33];
    const int b = blockIdx.z;
    const int c0 = blockIdx.y * 32;
    const int s0 = blockIdx.x * 32;
    const int tx = threadIdx.x, ty = threadIdx.y;
    const float* src = in + (size_t)b * 65536 * 192;
    float* dst = out + (size_t)b * 192 * 65536;
#pragma unroll
    for (int k = 0; k < 4; k++)
        t[ty + k * 8][tx] = src[(size_t)(s0 + ty + k * 8) * 192 + c0 + tx];
    __syncthreads();
#pragma unroll
    for (int k = 0; k < 4; k++)
        dst[(size_t)(c0 + ty + k * 8) * 65536 + s0 + tx] = t[tx][ty + k * 8];
}

// ---------------- weight transpose + fp32->bf16: W[K,N] -> Wt[N,K] ----------------
__global__ __launch_bounds__(256) void wtrans(const float* __restrict__ w,
                                              u16* __restrict__ wt, int K, int N) {
    int idx = blockIdx.x * 256 + threadIdx.x;
    if (idx >= K * N) return;
    int n = idx / K, k = idx % K;
    wt[idx] = f2bf(w[(size_t)k * N + n]);
}

// ---------------- LayerNorm over C=192, one token per wave ----------------
__global__ __launch_bounds__(256) void ln_k(const float* __restrict__ x,
                                            const float* __restrict__ g,
                                            const float* __restrict__ b,
                                            u16* __restrict__ o) {
    const int tid = threadIdx.x;
    const int l = tid & 63;
    const size_t tok = (size_t)blockIdx.x * 4 + (tid >> 6);
    const float* xr = x + tok * 192;
    float v0 = xr[l], v1 = xr[l + 64], v2 = xr[l + 128];
    float s = v0 + v1 + v2;
#pragma unroll
    for (int m = 1; m < 64; m <<= 1) s += __shfl_xor(s, m, 64);
    float mu = s * (1.f / 192.f);
    float d0 = v0 - mu, d1 = v1 - mu, d2 = v2 - mu;
    float q = d0 * d0 + d1 * d1 + d2 * d2;
#pragma unroll
    for (int m = 1; m < 64; m <<= 1) q += __shfl_xor(q, m, 64);
    float rs = rsqrtf(q * (1.f / 192.f) + 1e-5f);
    u16* orow = o + tok * 192;
    orow[l]       = f2bf(d0 * rs * g[l]       + b[l]);
    orow[l + 64]  = f2bf(d1 * rs * g[l + 64]  + b[l + 64]);
    orow[l + 128] = f2bf(d2 * rs * g[l + 128] + b[l + 128]);
}

// ---------------- MFMA GEMM: out = act(A[M,K] @ Wt[N,K]^T + bias) (+ residual) ----------------
// ACT: 0=none, 1=exact GELU.  RES: 0 -> bf16 out, 1 -> res[idx] += val (fp32)
template <int ACT, int RES>
__global__ __launch_bounds__(256) void gemm_k(const u16* __restrict__ A,
                                              const u16* __restrict__ Wt,
                                              const float* __restrict__ bias,
                                              float* __restrict__ res,
                                              u16* __restrict__ outb,
                                              int M, int N, int K) {
    __shared__ __align__(16) u16 As[128][40];
    __shared__ __align__(16) u16 Bs[64][40];
    const int t = threadIdx.x;
    const int l = t & 63;
    const int w = t >> 6;
    const size_t m0 = (size_t)blockIdx.y * 128;
    const int n0 = blockIdx.x * 64;
    f32x4 acc[2][4] = {};
    const int arow = t >> 1;
    const int aseg = t & 1;
    const int brow = t >> 2;
    const int bseg = t & 3;
    const int lc = l & 15;
    const int lg = l >> 4;
    for (int k0 = 0; k0 < K; k0 += 32) {
        *(u16x8*)&As[arow][aseg * 8]       = *(const u16x8*)&A[(m0 + arow) * K + k0 + aseg * 8];
        *(u16x8*)&As[arow][(aseg + 2) * 8] = *(const u16x8*)&A[(m0 + arow) * K + k0 + (aseg + 2) * 8];
        *(u16x8*)&Bs[brow][bseg * 8]       = *(const u16x8*)&Wt[(size_t)(n0 + brow) * K + k0 + bseg * 8];
        __syncthreads();
        bf16x8 af[2], bfr[4];
#pragma unroll
        for (int tm = 0; tm < 2; tm++) af[tm] = *(const bf16x8*)&As[w * 32 + tm * 16 + lc][lg * 8];
#pragma unroll
        for (int tn = 0; tn < 4; tn++) bfr[tn] = *(const bf16x8*)&Bs[tn * 16 + lc][lg * 8];
#pragma unroll
        for (int tm = 0; tm < 2; tm++)
#pragma unroll
            for (int tn = 0; tn < 4; tn++)
                acc[tm][tn] = __builtin_amdgcn_mfma_f32_16x16x32_bf16(af[tm], bfr[tn], acc[tm][tn], 0, 0, 0);
        __syncthreads();
    }
#pragma unroll
    for (int tm = 0; tm < 2; tm++)
#pragma unroll
        for (int tn = 0; tn < 4; tn++)
#pragma unroll
            for (int r = 0; r < 4; r++) {
                int row = w * 32 + tm * 16 + (lg << 2) + r;
                int col = n0 + tn * 16 + lc;
                size_t idx = (m0 + row) * (size_t)N + col;
                float v = acc[tm][tn][r] + bias[col];
                if (ACT == 1) v = 0.5f * v * (1.0f + erff(v * 0.70710678118654752f));
                if (RES) res[idx] = res[idx] + v;
                else outb[idx] = f2bf(v);
            }
}

// ---------------- windowed attention: 1 wave per (window, head) ----------------
__global__ __launch_bounds__(64) void attn_k(const u16* __restrict__ qkv,
                                             const float* __restrict__ rpb,
                                             u16* __restrict__ aout, int shifted) {
    __shared__ __align__(16) u16 Qs[64][40];
    __shared__ __align__(16) u16 Ks[64][40];
    __shared__ __align__(16) u16 Vt[32][72];
    __shared__ __align__(16) u16 Ps[64][72];
    const int l = threadIdx.x;
    const int head = blockIdx.x;
    const int wy = blockIdx.y;
    const int b = wy >> 10, widx = wy & 1023;
    const int wh = widx >> 5, ww = widx & 31;
    const int soff = shifted ? 4 : 0;
    const int lc = l & 15;
    const int lg = l >> 4;

    {   // stage this lane's token
        int i1 = l >> 3, j1 = l & 7;
        int hh = (wh * 8 + i1 + soff) & 255;
        int wc = (ww * 8 + j1 + soff) & 255;
        size_t tok = ((size_t)b * 256 + hh) * 256 + wc;
        const u16* base = qkv + tok * 576 + head * 32;
        u16x8 q[4], k[4], v[4];
#pragma unroll
        for (int s = 0; s < 4; s++) {
            q[s] = *(const u16x8*)(base + s * 8);
            k[s] = *(const u16x8*)(base + 192 + s * 8);
            v[s] = *(const u16x8*)(base + 384 + s * 8);
        }
#pragma unroll
        for (int s = 0; s < 4; s++) {
            *(u16x8*)&Qs[l][s * 8] = q[s];
            *(u16x8*)&Ks[l][s * 8] = k[s];
        }
#pragma unroll
        for (int s = 0; s < 4; s++)
#pragma unroll
            for (int e = 0; e < 8; e++) Vt[s * 8 + e][l] = v[s][e];
    }
    __syncthreads();

    f32x4 acc[4][4] = {};
    {
        bf16x8 qa[4], kb[4];
#pragma unroll
        for (int tm = 0; tm < 4; tm++) qa[tm] = *(const bf16x8*)&Qs[tm * 16 + lc][lg * 8];
#pragma unroll
        for (int tn = 0; tn < 4; tn++) kb[tn] = *(const bf16x8*)&Ks[tn * 16 + lc][lg * 8];
#pragma unroll
        for (int tm = 0; tm < 4; tm++)
#pragma unroll
            for (int tn = 0; tn < 4; tn++)
                acc[tm][tn] = __builtin_amdgcn_mfma_f32_16x16x32_bf16(qa[tm], kb[tn], acc[tm][tn], 0, 0, 0);
    }

    const float scale = 0.17677669529663687f; // 32^-0.5
    const float* rp = rpb + head * 225;
#pragma unroll
    for (int tm = 0; tm < 4; tm++) {
#pragma unroll
        for (int r = 0; r < 4; r++) {
            int p = tm * 16 + (lg << 2) + r;
            int pi = p >> 3, pj = p & 7;
            float sv[4];
#pragma unroll
            for (int tn = 0; tn < 4; tn++) {
                int qq = tn * 16 + lc;
                int qi = qq >> 3, qj = qq & 7;
                float xv = acc[tm][tn][r] * scale + rp[(pi - qi + 7) * 15 + (pj - qj + 7)];
                if (shifted) {
                    bool msk = (wh == 31 && ((pi < 4) != (qi < 4))) ||
                               (ww == 31 && ((pj < 4) != (qj < 4)));
                    if (msk) xv = -1e30f;
                }
                sv[tn] = xv;
            }
            float mx = fmaxf(fmaxf(sv[0], sv[1]), fmaxf(sv[2], sv[3]));
#pragma unroll
            for (int m = 1; m < 16; m <<= 1) mx = fmaxf(mx, __shfl_xor(mx, m, 64));
            float sum = 0.f;
#pragma unroll
            for (int tn = 0; tn < 4; tn++) { sv[tn] = __expf(sv[tn] - mx); sum += sv[tn]; }
#pragma unroll
            for (int m = 1; m < 16; m <<= 1) sum += __shfl_xor(sum, m, 64);
            float inv = 1.0f / sum;
#pragma unroll
            for (int tn = 0; tn < 4; tn++) Ps[p][tn * 16 + lc] = f2bf(sv[tn] * inv);
        }
    }
    __syncthreads();

    f32x4 o[4][2] = {};
#pragma unroll
    for (int kk = 0; kk < 2; kk++) {
        bf16x8 pa[4], vb[2];
#pragma unroll
        for (int tm = 0; tm < 4; tm++) pa[tm] = *(const bf16x8*)&Ps[tm * 16 + lc][kk * 32 + lg * 8];
#pragma unroll
        for (int tn = 0; tn < 2; tn++) vb[tn] = *(const bf16x8*)&Vt[tn * 16 + lc][kk * 32 + lg * 8];
#pragma unroll
        for (int tm = 0; tm < 4; tm++)
#pragma unroll
            for (int tn = 0; tn < 2; tn++)
                o[tm][tn] = __builtin_amdgcn_mfma_f32_16x16x32_bf16(pa[tm], vb[tn], o[tm][tn], 0, 0, 0);
    }
#pragma unroll
    for (int tm = 0; tm < 4; tm++)
#pragma unroll
        for (int r = 0; r < 4; r++) {
            int p = tm * 16 + (lg << 2) + r;
            int pi = p >> 3, pj = p & 7;
            int h2 = (wh * 8 + pi + soff) & 255;
            int w2 = (ww * 8 + pj + soff) & 255;
            size_t t2 = ((size_t)b * 256 + h2) * 256 + w2;
#pragma unroll
            for (int tn = 0; tn < 2; tn++)
                aout[t2 * 192 + head * 32 + tn * 16 + lc] = f2bf(o[tm][tn][r]);
        }
}

extern "C" void kernel_launch(void* const* d_in, const int* in_sizes, int n_in,
                              void* d_out, int out_size, void* d_ws, size_t ws_size,
                              hipStream_t stream) {
    (void)in_sizes; (void)n_in; (void)out_size; (void)ws_size;
    const float* x_in = (const float*)d_in[0];
    const size_t Ntok = (size_t)2 * 256 * 256; // 131072
    const int M = (int)Ntok;

    char* ws = (char*)d_ws;
    float* xbuf = (float*)ws;                       // 100,663,296 B
    u16* lnbuf = (u16*)(ws + 100663296);            //  50,331,648 B (also attn out)
    u16* big   = (u16*)(ws + 150994944);            // 201,326,592 B (qkv / mlp mid)
    u16* wts   = (u16*)(ws + 352321536);            // bf16 transposed weights

    // per-block weight offsets (elements)
    // qkvt: 576*192=110592 | projt: 192*192=36864 | w1t: 768*192=147456 | w2t: 192*768=147456
    u16* qkvt[2]; u16* projt[2]; u16* w1t[2]; u16* w2t[2];
    for (int bi = 0; bi < 2; bi++) {
        size_t base = (size_t)bi * 442368;
        qkvt[bi]  = wts + base;
        projt[bi] = wts + base + 110592;
        w1t[bi]   = wts + base + 147456;
        w2t[bi]   = wts + base + 294912;
    }

    // input NCHW -> NHWC
    transpose_in<<<dim3(2048, 6, 2), dim3(32, 8), 0, stream>>>(x_in, xbuf);

    // weight prep
    for (int bi = 0; bi < 2; bi++) {
        const int base = 1 + bi * 13;
        const float* qkv_w  = (const float*)d_in[base + 2];
        const float* proj_w = (const float*)d_in[base + 5];
        const float* w1     = (const float*)d_in[base + 9];
        const float* w2     = (const float*)d_in[base + 11];
        wtrans<<<dim3((110592 + 255) / 256), 256, 0, stream>>>(qkv_w,  qkvt[bi],  192, 576);
        wtrans<<<dim3((36864  + 255) / 256), 256, 0, stream>>>(proj_w, projt[bi], 192, 192);
        wtrans<<<dim3((147456 + 255) / 256), 256, 0, stream>>>(w1,     w1t[bi],   192, 768);
        wtrans<<<dim3((147456 + 255) / 256), 256, 0, stream>>>(w2,     w2t[bi],   768, 192);
    }

    const int lnBlocks = (int)(Ntok / 4);
    for (int bi = 0; bi < 2; bi++) {
        const int base = 1 + bi * 13;
        const float* ln1_g  = (const float*)d_in[base + 0];
        const float* ln1_b  = (const float*)d_in[base + 1];
        const float* qkv_b  = (const float*)d_in[base + 3];
        const float* rpb    = (const float*)d_in[base + 4];
        const float* proj_b = (const float*)d_in[base + 6];
        const float* ln2_g  = (const float*)d_in[base + 7];
        const float* ln2_b  = (const float*)d_in[base + 8];
        const float* b1     = (const float*)d_in[base + 10];
        const float* b2     = (const float*)d_in[base + 12];

        // LN1
        ln_k<<<lnBlocks, 256, 0, stream>>>(xbuf, ln1_g, ln1_b, lnbuf);
        // QKV GEMM -> big (bf16, N=576)
        gemm_k<0, 0><<<dim3(9, 1024), 256, 0, stream>>>(lnbuf, qkvt[bi], qkv_b,
                                                        nullptr, big, M, 576, 192);
        // attention -> lnbuf (bf16, N=192)
        attn_k<<<dim3(6, 2048), 64, 0, stream>>>(big, rpb, lnbuf, bi);
        // proj GEMM + residual into xbuf (fp32)
        gemm_k<0, 1><<<dim3(3, 1024), 256, 0, stream>>>(lnbuf, projt[bi], proj_b,
                                                        xbuf, nullptr, M, 192, 192);
        // LN2
        ln_k<<<lnBlocks, 256, 0, stream>>>(xbuf, ln2_g, ln2_b, lnbuf);
        // MLP1 + GELU -> big (bf16, N=768)
        gemm_k<1, 0><<<dim3(12, 1024), 256, 0, stream>>>(lnbuf, w1t[bi], b1,
                                                         nullptr, big, M, 768, 192);
        // MLP2 + residual into xbuf
        gemm_k<0, 1><<<dim3(3, 1024), 256, 0, stream>>>(big, w2t[bi], b2,
                                                        xbuf, nullptr, M, 192, 768);
    }

    // NHWC -> NCHW into d_out
    transpose_out<<<dim3(2048, 6, 2), dim3(32, 8), 0, stream>>>(xbuf, (float*)d_out);
}

// Round 2
// 1148.258 us; speedup vs baseline: 1.1133x; 1.1133x over previous
//
#include <hip/hip_runtime.h>
#include <math.h>

typedef unsigned short u16;
typedef u16 u16x8 __attribute__((ext_vector_type(8)));
typedef __bf16 bf16x8 __attribute__((ext_vector_type(8)));
typedef float f32x4 __attribute__((ext_vector_type(4)));

__device__ __forceinline__ u16 f2bf(float f) {
    union { float f; unsigned u; } v; v.f = f;
    unsigned r = v.u + 0x7fffu + ((v.u >> 16) & 1u);
    return (u16)(r >> 16);
}

// async global->LDS, 16B per lane (dest must be wave-uniform base + lane*16)
__device__ __forceinline__ void gload16(const void* g, void* l) {
    __builtin_amdgcn_global_load_lds((const __attribute__((address_space(1))) void*)g,
                                     (__attribute__((address_space(3))) void*)l,
                                     16, 0, 0);
}

// ---------------- NCHW -> NHWC transpose (fp32) ----------------
__global__ __launch_bounds__(256) void transpose_in(const float* __restrict__ in,
                                                    float* __restrict__ out) {
    __shared__ float t[32][33];
    const int b = blockIdx.z;
    const int c0 = blockIdx.y * 32;
    const int s0 = blockIdx.x * 32;
    const int tx = threadIdx.x, ty = threadIdx.y; // 32 x 8
    const float* src = in + (size_t)b * 192 * 65536;
    float* dst = out + (size_t)b * 65536 * 192;
#pragma unroll
    for (int k = 0; k < 4; k++)
        t[ty + k * 8][tx] = src[(size_t)(c0 + ty + k * 8) * 65536 + s0 + tx];
    __syncthreads();
#pragma unroll
    for (int k = 0; k < 4; k++)
        dst[(size_t)(s0 + ty + k * 8) * 192 + c0 + tx] = t[tx][ty + k * 8];
}

// ---------------- NHWC -> NCHW transpose (fp32) ----------------
__global__ __launch_bounds__(256) void transpose_out(const float* __restrict__ in,
                                                     float* __restrict__ out) {
    __shared__ float t[32][33];
    const int b = blockIdx.z;
    const int c0 = blockIdx.y * 32;
    const int s0 = blockIdx.x * 32;
    const int tx = threadIdx.x, ty = threadIdx.y;
    const float* src = in + (size_t)b * 65536 * 192;
    float* dst = out + (size_t)b * 192 * 65536;
#pragma unroll
    for (int k = 0; k < 4; k++)
        t[ty + k * 8][tx] = src[(size_t)(s0 + ty + k * 8) * 192 + c0 + tx];
    __syncthreads();
#pragma unroll
    for (int k = 0; k < 4; k++)
        dst[(size_t)(c0 + ty + k * 8) * 65536 + s0 + tx] = t[tx][ty + k * 8];
}

// ---------------- weight transpose + fp32->bf16: W[K,N] -> Wt[N,K] ----------------
__global__ __launch_bounds__(256) void wtrans(const float* __restrict__ w,
                                              u16* __restrict__ wt, int K, int N) {
    int idx = blockIdx.x * 256 + threadIdx.x;
    if (idx >= K * N) return;
    int n = idx / K, k = idx % K;
    wt[idx] = f2bf(w[(size_t)k * N + n]);
}

// ---------------- LayerNorm over C=192, one token per wave ----------------
__global__ __launch_bounds__(256) void ln_k(const float* __restrict__ x,
                                            const float* __restrict__ g,
                                            const float* __restrict__ b,
                                            u16* __restrict__ o) {
    const int tid = threadIdx.x;
    const int l = tid & 63;
    const size_t tok = (size_t)blockIdx.x * 4 + (tid >> 6);
    const float* xr = x + tok * 192;
    float v0 = xr[l], v1 = xr[l + 64], v2 = xr[l + 128];
    float s = v0 + v1 + v2;
#pragma unroll
    for (int m = 1; m < 64; m <<= 1) s += __shfl_xor(s, m, 64);
    float mu = s * (1.f / 192.f);
    float d0 = v0 - mu, d1 = v1 - mu, d2 = v2 - mu;
    float q = d0 * d0 + d1 * d1 + d2 * d2;
#pragma unroll
    for (int m = 1; m < 64; m <<= 1) q += __shfl_xor(q, m, 64);
    float rs = rsqrtf(q * (1.f / 192.f) + 1e-5f);
    u16* orow = o + tok * 192;
    orow[l]       = f2bf(d0 * rs * g[l]       + b[l]);
    orow[l + 64]  = f2bf(d1 * rs * g[l + 64]  + b[l + 64]);
    orow[l + 128] = f2bf(d2 * rs * g[l + 128] + b[l + 128]);
}

// ---------------- MFMA GEMM (2-phase pipelined, global_load_lds staging) ----------------
// out = act(A[M,K] @ Wt[N,K]^T + bias)  (+ residual)
// ACT: 0=none, 1=exact GELU.  RES: 0 -> bf16 out (LDS-bounced coalesced), 1 -> res[idx] += val (fp32)
template <int ACT, int RES, int K>
__global__ __launch_bounds__(256) void gemm_k(const u16* __restrict__ A,
                                              const u16* __restrict__ Wt,
                                              const float* __restrict__ bias,
                                              float* __restrict__ res,
                                              u16* __restrict__ outb,
                                              int N, int Nb) {
    __shared__ __align__(16) u16 As[2][128 * 32];  // 2 x 8 KB, linear [128][32]
    __shared__ __align__(16) u16 Bs[2][64 * 32];   // 2 x 4 KB, linear [64][32]
    const int t = threadIdx.x;
    const int l = t & 63;
    const int w = t >> 6;
    // XCD-aware bijective swizzle (grid is always a multiple of 8)
    const int nwg = gridDim.x;
    const int q8 = nwg >> 3;
    const int wg = (blockIdx.x & 7) * q8 + (blockIdx.x >> 3);
    const int bn = wg % Nb, bm = wg / Nb;
    const size_t m0 = (size_t)bm * 128;
    const int n0 = bn * 64;
    const int lc = l & 15;
    const int lg = l >> 4;

    const u16* ga = A + (m0 + (t >> 2)) * K + (t & 3) * 8;
    const u16* gb = Wt + ((size_t)(n0 + (t >> 2))) * K + (t & 3) * 8;

    f32x4 acc[2][4] = {};

#define STAGE(buf, k0)                                              \
    do {                                                            \
        gload16(ga + (k0), &As[buf][t * 8]);                        \
        gload16(ga + (size_t)64 * K + (k0), &As[buf][2048 + t * 8]);\
        gload16(gb + (k0), &Bs[buf][t * 8]);                        \
    } while (0)

#define COMPUTE(buf)                                                                     \
    do {                                                                                 \
        bf16x8 af[2], bfr[4];                                                            \
        _Pragma("unroll")                                                                \
        for (int tm = 0; tm < 2; tm++)                                                   \
            af[tm] = *(const bf16x8*)&As[buf][(w * 32 + tm * 16 + lc) * 32 + lg * 8];    \
        _Pragma("unroll")                                                                \
        for (int tn = 0; tn < 4; tn++)                                                   \
            bfr[tn] = *(const bf16x8*)&Bs[buf][(tn * 16 + lc) * 32 + lg * 8];            \
        _Pragma("unroll")                                                                \
        for (int tm = 0; tm < 2; tm++)                                                   \
            _Pragma("unroll")                                                            \
            for (int tn = 0; tn < 4; tn++)                                               \
                acc[tm][tn] = __builtin_amdgcn_mfma_f32_16x16x32_bf16(af[tm], bfr[tn],   \
                                                                     acc[tm][tn], 0, 0, 0); \
    } while (0)

    constexpr int KS = K / 32;
    STAGE(0, 0);
    __syncthreads();  // drains vmcnt(0)
#pragma unroll
    for (int ks = 0; ks < KS - 1; ks++) {
        const int cur = ks & 1;
        STAGE(cur ^ 1, (ks + 1) * 32);  // issue next-tile loads BEFORE compute
        COMPUTE(cur);
        __syncthreads();                // vmcnt(0)+lgkmcnt(0) drain + barrier
    }
    COMPUTE((KS - 1) & 1);
#undef STAGE
#undef COMPUTE

    float bv[4];
#pragma unroll
    for (int tn = 0; tn < 4; tn++) bv[tn] = bias[n0 + tn * 16 + lc];

    if (RES) {
#pragma unroll
        for (int tm = 0; tm < 2; tm++)
#pragma unroll
            for (int tn = 0; tn < 4; tn++)
#pragma unroll
                for (int r = 0; r < 4; r++) {
                    int row = w * 32 + tm * 16 + (lg << 2) + r;
                    int col = n0 + tn * 16 + lc;
                    size_t idx = (m0 + row) * (size_t)N + col;
                    res[idx] = res[idx] + acc[tm][tn][r] + bv[tn];
                }
    } else {
        __syncthreads();  // all waves done reading K-loop LDS
        u16* Ct = &As[0][0];  // 16 KB = [128][64] u16
#pragma unroll
        for (int tm = 0; tm < 2; tm++)
#pragma unroll
            for (int tn = 0; tn < 4; tn++)
#pragma unroll
                for (int r = 0; r < 4; r++) {
                    int row = w * 32 + tm * 16 + (lg << 2) + r;
                    int col = tn * 16 + lc;
                    float v = acc[tm][tn][r] + bv[tn];
                    if (ACT == 1) v = 0.5f * v * (1.0f + erff(v * 0.70710678118654752f));
                    Ct[row * 64 + col] = f2bf(v);
                }
        __syncthreads();
#pragma unroll
        for (int i = 0; i < 4; i++) {
            int row = (t >> 3) + i * 32, seg = t & 7;
            *(u16x8*)&outb[(m0 + row) * (size_t)N + n0 + seg * 8] =
                *(const u16x8*)&Ct[row * 64 + seg * 8];
        }
    }
}

// ---------------- windowed attention: 1 wave per (window, head) ----------------
// Q/K fragments loaded directly from global (row-reads, no transpose needed);
// only V^T and P go through LDS -> ~14 KB/block -> ~11 waves/CU occupancy.
__global__ __launch_bounds__(64) void attn_k(const u16* __restrict__ qkv,
                                             const float* __restrict__ rpb,
                                             u16* __restrict__ aout, int shifted) {
    __shared__ __align__(16) u16 Vt[32][72];
    __shared__ __align__(16) u16 Ps[64][72];
    const int l = threadIdx.x;
    const int head = blockIdx.x;
    const int wy = blockIdx.y;
    const int b = wy >> 10, widx = wy & 1023;
    const int wh = widx >> 5, ww = widx & 31;
    const int soff = shifted ? 4 : 0;
    const int lc = l & 15;
    const int lg = l >> 4;

    // stage this lane's token V (transposed)
    {
        int i1 = l >> 3, j1 = l & 7;
        int hh = (wh * 8 + i1 + soff) & 255;
        int wc = (ww * 8 + j1 + soff) & 255;
        const u16* base = qkv + (((size_t)b * 256 + hh) * 256 + wc) * 576 + head * 32 + 384;
#pragma unroll
        for (int s = 0; s < 4; s++) {
            u16x8 v = *(const u16x8*)(base + s * 8);
#pragma unroll
            for (int e = 0; e < 8; e++) Vt[s * 8 + e][l] = v[e];
        }
    }

    // Q/K fragments direct from global
    bf16x8 qa[4], kb[4];
#pragma unroll
    for (int tm = 0; tm < 4; tm++) {
        int p = tm * 16 + lc;
        int pi = p >> 3, pj = p & 7;
        int hh = (wh * 8 + pi + soff) & 255;
        int wc = (ww * 8 + pj + soff) & 255;
        const u16* tp = qkv + (((size_t)b * 256 + hh) * 256 + wc) * 576 + head * 32;
        qa[tm] = *(const bf16x8*)(tp + lg * 8);
        kb[tm] = *(const bf16x8*)(tp + 192 + lg * 8);
    }

    f32x4 acc[4][4] = {};
    __builtin_amdgcn_s_setprio(1);
#pragma unroll
    for (int tm = 0; tm < 4; tm++)
#pragma unroll
        for (int tn = 0; tn < 4; tn++)
            acc[tm][tn] = __builtin_amdgcn_mfma_f32_16x16x32_bf16(qa[tm], kb[tn], acc[tm][tn], 0, 0, 0);
    __builtin_amdgcn_s_setprio(0);

    const float scale = 0.17677669529663687f; // 32^-0.5
    const float* rp = rpb + head * 225;
#pragma unroll
    for (int tm = 0; tm < 4; tm++) {
#pragma unroll
        for (int r = 0; r < 4; r++) {
            int p = tm * 16 + (lg << 2) + r;
            int pi = p >> 3, pj = p & 7;
            float sv[4];
#pragma unroll
            for (int tn = 0; tn < 4; tn++) {
                int qq = tn * 16 + lc;
                int qi = qq >> 3, qj = qq & 7;
                float xv = acc[tm][tn][r] * scale + rp[(pi - qi + 7) * 15 + (pj - qj + 7)];
                if (shifted) {
                    bool msk = (wh == 31 && ((pi < 4) != (qi < 4))) ||
                               (ww == 31 && ((pj < 4) != (qj < 4)));
                    if (msk) xv = -1e30f;
                }
                sv[tn] = xv;
            }
            float mx = fmaxf(fmaxf(sv[0], sv[1]), fmaxf(sv[2], sv[3]));
#pragma unroll
            for (int m = 1; m < 16; m <<= 1) mx = fmaxf(mx, __shfl_xor(mx, m, 64));
            float sum = 0.f;
#pragma unroll
            for (int tn = 0; tn < 4; tn++) { sv[tn] = __expf(sv[tn] - mx); sum += sv[tn]; }
#pragma unroll
            for (int m = 1; m < 16; m <<= 1) sum += __shfl_xor(sum, m, 64);
            float inv = 1.0f / sum;
#pragma unroll
            for (int tn = 0; tn < 4; tn++) Ps[p][tn * 16 + lc] = f2bf(sv[tn] * inv);
        }
    }
    __syncthreads();

    f32x4 o[4][2] = {};
    {
        bf16x8 pa[4], vb[2];
#pragma unroll
        for (int kk = 0; kk < 2; kk++) {
#pragma unroll
            for (int tm = 0; tm < 4; tm++) pa[tm] = *(const bf16x8*)&Ps[tm * 16 + lc][kk * 32 + lg * 8];
#pragma unroll
            for (int tn = 0; tn < 2; tn++) vb[tn] = *(const bf16x8*)&Vt[tn * 16 + lc][kk * 32 + lg * 8];
            __builtin_amdgcn_s_setprio(1);
#pragma unroll
            for (int tm = 0; tm < 4; tm++)
#pragma unroll
                for (int tn = 0; tn < 2; tn++)
                    o[tm][tn] = __builtin_amdgcn_mfma_f32_16x16x32_bf16(pa[tm], vb[tn], o[tm][tn], 0, 0, 0);
            __builtin_amdgcn_s_setprio(0);
        }
    }
#pragma unroll
    for (int tm = 0; tm < 4; tm++)
#pragma unroll
        for (int r = 0; r < 4; r++) {
            int p = tm * 16 + (lg << 2) + r;
            int pi = p >> 3, pj = p & 7;
            int h2 = (wh * 8 + pi + soff) & 255;
            int w2 = (ww * 8 + pj + soff) & 255;
            size_t t2 = ((size_t)b * 256 + h2) * 256 + w2;
#pragma unroll
            for (int tn = 0; tn < 2; tn++)
                aout[t2 * 192 + head * 32 + tn * 16 + lc] = f2bf(o[tm][tn][r]);
        }
}

extern "C" void kernel_launch(void* const* d_in, const int* in_sizes, int n_in,
                              void* d_out, int out_size, void* d_ws, size_t ws_size,
                              hipStream_t stream) {
    (void)in_sizes; (void)n_in; (void)out_size; (void)ws_size;
    const float* x_in = (const float*)d_in[0];
    const size_t Ntok = (size_t)2 * 256 * 256; // 131072

    char* ws = (char*)d_ws;
    float* xbuf = (float*)ws;                       // 100,663,296 B
    u16* lnbuf = (u16*)(ws + 100663296);            //  50,331,648 B (also attn out)
    u16* big   = (u16*)(ws + 150994944);            // 201,326,592 B (qkv / mlp mid)
    u16* wts   = (u16*)(ws + 352321536);            // bf16 transposed weights

    u16* qkvt[2]; u16* projt[2]; u16* w1t[2]; u16* w2t[2];
    for (int bi = 0; bi < 2; bi++) {
        size_t base = (size_t)bi * 442368;
        qkvt[bi]  = wts + base;
        projt[bi] = wts + base + 110592;
        w1t[bi]   = wts + base + 147456;
        w2t[bi]   = wts + base + 294912;
    }

    // input NCHW -> NHWC
    transpose_in<<<dim3(2048, 6, 2), dim3(32, 8), 0, stream>>>(x_in, xbuf);

    // weight prep
    for (int bi = 0; bi < 2; bi++) {
        const int base = 1 + bi * 13;
        wtrans<<<dim3((110592 + 255) / 256), 256, 0, stream>>>((const float*)d_in[base + 2],  qkvt[bi],  192, 576);
        wtrans<<<dim3((36864  + 255) / 256), 256, 0, stream>>>((const float*)d_in[base + 5],  projt[bi], 192, 192);
        wtrans<<<dim3((147456 + 255) / 256), 256, 0, stream>>>((const float*)d_in[base + 9],  w1t[bi],   192, 768);
        wtrans<<<dim3((147456 + 255) / 256), 256, 0, stream>>>((const float*)d_in[base + 11], w2t[bi],   768, 192);
    }

    const int lnBlocks = (int)(Ntok / 4);
    for (int bi = 0; bi < 2; bi++) {
        const int base = 1 + bi * 13;
        const float* ln1_g  = (const float*)d_in[base + 0];
        const float* ln1_b  = (const float*)d_in[base + 1];
        const float* qkv_b  = (const float*)d_in[base + 3];
        const float* rpb    = (const float*)d_in[base + 4];
        const float* proj_b = (const float*)d_in[base + 6];
        const float* ln2_g  = (const float*)d_in[base + 7];
        const float* ln2_b  = (const float*)d_in[base + 8];
        const float* b1     = (const float*)d_in[base + 10];
        const float* b2     = (const float*)d_in[base + 12];

        // LN1
        ln_k<<<lnBlocks, 256, 0, stream>>>(xbuf, ln1_g, ln1_b, lnbuf);
        // QKV GEMM -> big (bf16, N=576)
        gemm_k<0, 0, 192><<<9 * 1024, 256, 0, stream>>>(lnbuf, qkvt[bi], qkv_b,
                                                        nullptr, big, 576, 9);
        // attention -> lnbuf (bf16, N=192)
        attn_k<<<dim3(6, 2048), 64, 0, stream>>>(big, rpb, lnbuf, bi);
        // proj GEMM + residual into xbuf (fp32)
        gemm_k<0, 1, 192><<<3 * 1024, 256, 0, stream>>>(lnbuf, projt[bi], proj_b,
                                                        xbuf, nullptr, 192, 3);
        // LN2
        ln_k<<<lnBlocks, 256, 0, stream>>>(xbuf, ln2_g, ln2_b, lnbuf);
        // MLP1 + GELU -> big (bf16, N=768)
        gemm_k<1, 0, 192><<<12 * 1024, 256, 0, stream>>>(lnbuf, w1t[bi], b1,
                                                         nullptr, big, 768, 12);
        // MLP2 + residual into xbuf
        gemm_k<0, 1, 768><<<3 * 1024, 256, 0, stream>>>(big, w2t[bi], b2,
                                                        xbuf, nullptr, 192, 768 / 256 * 1); // Nb=3
    }

    // NHWC -> NCHW into d_out
    transpose_out<<<dim3(2048, 6, 2), dim3(32, 8), 0, stream>>>(xbuf, (float*)d_out);
}

// Round 3
// 992.826 us; speedup vs baseline: 1.2876x; 1.1566x over previous
//
#include <hip/hip_runtime.h>
#include <math.h>

typedef unsigned short u16;
typedef u16 u16x8 __attribute__((ext_vector_type(8)));
typedef __bf16 bf16x8 __attribute__((ext_vector_type(8)));
typedef float f32x4 __attribute__((ext_vector_type(4)));

__device__ __forceinline__ u16 f2bf(float f) {
    union { float f; unsigned u; } v; v.f = f;
    unsigned r = v.u + 0x7fffu + ((v.u >> 16) & 1u);
    return (u16)(r >> 16);
}

__device__ __forceinline__ void gload16(const void* g, void* l) {
    __builtin_amdgcn_global_load_lds((const __attribute__((address_space(1))) void*)g,
                                     (__attribute__((address_space(3))) void*)l,
                                     16, 0, 0);
}

__device__ __forceinline__ float redsum16(float s) {
    s += __shfl_xor(s, 1, 64);
    s += __shfl_xor(s, 2, 64);
    s += __shfl_xor(s, 4, 64);
    s += __shfl_xor(s, 8, 64);
    return s;
}

// ---------------- NCHW -> NHWC transpose (fp32) ----------------
__global__ __launch_bounds__(256) void transpose_in(const float* __restrict__ in,
                                                    float* __restrict__ out) {
    __shared__ float t[32][33];
    const int b = blockIdx.z;
    const int c0 = blockIdx.y * 32;
    const int s0 = blockIdx.x * 32;
    const int tx = threadIdx.x, ty = threadIdx.y;
    const float* src = in + (size_t)b * 192 * 65536;
    float* dst = out + (size_t)b * 65536 * 192;
#pragma unroll
    for (int k = 0; k < 4; k++)
        t[ty + k * 8][tx] = src[(size_t)(c0 + ty + k * 8) * 65536 + s0 + tx];
    __syncthreads();
#pragma unroll
    for (int k = 0; k < 4; k++)
        dst[(size_t)(s0 + ty + k * 8) * 192 + c0 + tx] = t[tx][ty + k * 8];
}

__global__ __launch_bounds__(256) void transpose_out(const float* __restrict__ in,
                                                     float* __restrict__ out) {
    __shared__ float t[32][33];
    const int b = blockIdx.z;
    const int c0 = blockIdx.y * 32;
    const int s0 = blockIdx.x * 32;
    const int tx = threadIdx.x, ty = threadIdx.y;
    const float* src = in + (size_t)b * 65536 * 192;
    float* dst = out + (size_t)b * 192 * 65536;
#pragma unroll
    for (int k = 0; k < 4; k++)
        t[ty + k * 8][tx] = src[(size_t)(s0 + ty + k * 8) * 192 + c0 + tx];
    __syncthreads();
#pragma unroll
    for (int k = 0; k < 4; k++)
        dst[(size_t)(c0 + ty + k * 8) * 65536 + s0 + tx] = t[tx][ty + k * 8];
}

// ---------------- weight transpose + fp32->bf16: W[K,N] -> Wt[N,K] ----------------
__global__ __launch_bounds__(256) void wtrans(const float* __restrict__ w,
                                              u16* __restrict__ wt, int K, int N) {
    int idx = blockIdx.x * 256 + threadIdx.x;
    if (idx >= K * N) return;
    int n = idx / K, k = idx % K;
    wt[idx] = f2bf(w[(size_t)k * N + n]);
}

// ---------------- LayerNorm over C=192, one token per wave (block-1 LN1 only) ----------------
__global__ __launch_bounds__(256) void ln_k(const float* __restrict__ x,
                                            const float* __restrict__ g,
                                            const float* __restrict__ b,
                                            u16* __restrict__ o) {
    const int tid = threadIdx.x;
    const int l = tid & 63;
    const size_t tok = (size_t)blockIdx.x * 4 + (tid >> 6);
    const float* xr = x + tok * 192;
    float v0 = xr[l], v1 = xr[l + 64], v2 = xr[l + 128];
    float s = v0 + v1 + v2;
#pragma unroll
    for (int m = 1; m < 64; m <<= 1) s += __shfl_xor(s, m, 64);
    float mu = s * (1.f / 192.f);
    float d0 = v0 - mu, d1 = v1 - mu, d2 = v2 - mu;
    float q = d0 * d0 + d1 * d1 + d2 * d2;
#pragma unroll
    for (int m = 1; m < 64; m <<= 1) q += __shfl_xor(q, m, 64);
    float rs = rsqrtf(q * (1.f / 192.f) + 1e-5f);
    u16* orow = o + tok * 192;
    orow[l]       = f2bf(d0 * rs * g[l]       + b[l]);
    orow[l + 64]  = f2bf(d1 * rs * g[l + 64]  + b[l + 64]);
    orow[l + 128] = f2bf(d2 * rs * g[l + 128] + b[l + 128]);
}

// ---------------- GEMM, K=192, BN=64: B fully LDS-resident, A streamed to regs ----------------
// out(bf16) = act(A[M,192] @ Wt[N,192]^T + bias); ACT: 0=none, 1=exact GELU
template <int ACT>
__global__ __launch_bounds__(256, 2) void gemm_small(const u16* __restrict__ A,
                                                     const u16* __restrict__ Wt,
                                                     const float* __restrict__ bias,
                                                     u16* __restrict__ outb,
                                                     int N, int Nb) {
    __shared__ __align__(16) u16 Bs[64 * 192];  // 24 KB
    const int t = threadIdx.x, l = t & 63, w = t >> 6;
    const int nwg = gridDim.x, q8 = nwg >> 3;
    const int wg = (blockIdx.x & 7) * q8 + (blockIdx.x >> 3);  // XCD-chunked
    const int bn = wg % Nb, bm = wg / Nb;
    const size_t m0 = (size_t)bm * 128;
    const int n0 = bn * 64;
    const int lc = l & 15, lg = l >> 4;

    // stage B with XOR-swizzled (16B-chunk ^ row&7) global source, linear LDS dest
#pragma unroll
    for (int r = 0; r < 6; r++) {
        int f = r * 2048 + t * 8;          // u16 offset in Bs
        int row = f / 192;
        int c = ((f - row * 192) >> 3) ^ (row & 7);
        gload16(Wt + (size_t)(n0 + row) * 192 + c * 8, &Bs[f]);
    }
    // preload ALL A fragments to registers (independent of LDS)
    const u16* ga = A + (m0 + w * 32 + lc) * 192 + lg * 8;
    bf16x8 af[6][2];
#pragma unroll
    for (int ks = 0; ks < 6; ks++)
#pragma unroll
        for (int tm = 0; tm < 2; tm++)
            af[ks][tm] = *(const bf16x8*)(ga + tm * 3072 + ks * 32);

    f32x4 acc[2][4] = {};
    __syncthreads();
#pragma unroll
    for (int ks = 0; ks < 6; ks++) {
        bf16x8 bfr[4];
#pragma unroll
        for (int tn = 0; tn < 4; tn++) {
            int row = tn * 16 + lc;
            int p = (ks * 4 + lg) ^ (row & 7);
            bfr[tn] = *(const bf16x8*)&Bs[row * 192 + p * 8];
        }
#pragma unroll
        for (int tm = 0; tm < 2; tm++)
#pragma unroll
            for (int tn = 0; tn < 4; tn++)
                acc[tm][tn] = __builtin_amdgcn_mfma_f32_16x16x32_bf16(af[ks][tm], bfr[tn],
                                                                     acc[tm][tn], 0, 0, 0);
    }
    float bv[4];
#pragma unroll
    for (int tn = 0; tn < 4; tn++) bv[tn] = bias[n0 + tn * 16 + lc];
    __syncthreads();  // all waves done reading Bs
    u16* Ct = Bs;     // bounce buffer [128][72]
#pragma unroll
    for (int tm = 0; tm < 2; tm++)
#pragma unroll
        for (int tn = 0; tn < 4; tn++)
#pragma unroll
            for (int r = 0; r < 4; r++) {
                int row = w * 32 + tm * 16 + (lg << 2) + r;
                float v = acc[tm][tn][r] + bv[tn];
                if (ACT) v = 0.5f * v * (1.0f + erff(v * 0.70710678118654752f));
                Ct[row * 72 + tn * 16 + lc] = f2bf(v);
            }
    __syncthreads();
#pragma unroll
    for (int i = 0; i < 4; i++) {
        int row = i * 32 + (t >> 3), seg = t & 7;
        *(u16x8*)&outb[(m0 + row) * (size_t)N + n0 + seg * 8] =
            *(const u16x8*)&Ct[row * 72 + seg * 8];
    }
}

// ---------------- proj (K=192, N=192 full) + residual + fused LN2 ----------------
__global__ __launch_bounds__(256, 2) void proj_ln_k(const u16* __restrict__ A,
                                                    const u16* __restrict__ Wt,
                                                    const float* __restrict__ bias,
                                                    float* __restrict__ res,
                                                    const float* __restrict__ g,
                                                    const float* __restrict__ b,
                                                    u16* __restrict__ lnout) {
    __shared__ __align__(16) u16 Bs[192 * 192];  // 72 KB
    const int t = threadIdx.x, l = t & 63, w = t >> 6;
    const size_t m0 = (size_t)blockIdx.x * 128;
    const int lc = l & 15, lg = l >> 4;
#pragma unroll
    for (int r = 0; r < 18; r++) {
        int f = r * 2048 + t * 8;
        int row = f / 192;
        int c = ((f - row * 192) >> 3) ^ (row & 7);
        gload16(Wt + (size_t)row * 192 + c * 8, &Bs[f]);
    }
    const u16* ga = A + (m0 + w * 32 + lc) * 192 + lg * 8;
    bf16x8 af[6][2];
#pragma unroll
    for (int ks = 0; ks < 6; ks++)
#pragma unroll
        for (int tm = 0; tm < 2; tm++)
            af[ks][tm] = *(const bf16x8*)(ga + tm * 3072 + ks * 32);

    f32x4 acc[2][12] = {};
    __syncthreads();
#pragma unroll
    for (int ks = 0; ks < 6; ks++) {
        bf16x8 bfr[12];
#pragma unroll
        for (int tn = 0; tn < 12; tn++) {
            int row = tn * 16 + lc;
            int p = (ks * 4 + lg) ^ (row & 7);
            bfr[tn] = *(const bf16x8*)&Bs[row * 192 + p * 8];
        }
#pragma unroll
        for (int tm = 0; tm < 2; tm++)
#pragma unroll
            for (int tn = 0; tn < 12; tn++)
                acc[tm][tn] = __builtin_amdgcn_mfma_f32_16x16x32_bf16(af[ks][tm], bfr[tn],
                                                                     acc[tm][tn], 0, 0, 0);
    }
    float bv[12], gv[12], bb[12];
#pragma unroll
    for (int tn = 0; tn < 12; tn++) {
        bv[tn] = bias[tn * 16 + lc];
        gv[tn] = g[tn * 16 + lc];
        bb[tn] = b[tn * 16 + lc];
    }
#pragma unroll
    for (int tm = 0; tm < 2; tm++)
#pragma unroll
        for (int r = 0; r < 4; r++) {
            int row = w * 32 + tm * 16 + (lg << 2) + r;
            size_t base = (m0 + row) * 192;
            float v[12], s = 0.f;
#pragma unroll
            for (int tn = 0; tn < 12; tn++) {
                v[tn] = acc[tm][tn][r] + bv[tn] + res[base + tn * 16 + lc];
                s += v[tn];
            }
            s = redsum16(s);
            float mu = s * (1.f / 192.f);
            float q = 0.f;
#pragma unroll
            for (int tn = 0; tn < 12; tn++) { float d = v[tn] - mu; q += d * d; }
            q = redsum16(q);
            float rstd = rsqrtf(q * (1.f / 192.f) + 1e-5f);
#pragma unroll
            for (int tn = 0; tn < 12; tn++) {
                res[base + tn * 16 + lc] = v[tn];
                lnout[base + tn * 16 + lc] = f2bf((v[tn] - mu) * rstd * gv[tn] + bb[tn]);
            }
        }
}

// ---------------- MLP2 (K=768, N=192 full, BM=256, 8 waves) + residual (+ fused next-LN1) ----------------
template <int DO_LN>
__global__ __launch_bounds__(512, 2) void mlp2_k(const u16* __restrict__ A,
                                                 const u16* __restrict__ Wt,
                                                 const float* __restrict__ bias,
                                                 float* __restrict__ res,
                                                 const float* __restrict__ g,
                                                 const float* __restrict__ b,
                                                 u16* __restrict__ lnout) {
    __shared__ __align__(16) u16 Bs[2][192 * 128];  // 2 x 48 KB
    const int t = threadIdx.x, l = t & 63, w = t >> 6;
    const size_t m0 = (size_t)blockIdx.x * 256;
    const int lc = l & 15, lg = l >> 4;
    const u16* ga = A + (m0 + w * 32 + lc) * 768 + lg * 8;
    f32x4 acc[2][12] = {};
    bf16x8 af[26][2];

#define STB(bufi, kb)                                                         \
    do {                                                                      \
        _Pragma("unroll") for (int rr = 0; rr < 6; rr++) {                    \
            int f = rr * 4096 + t * 8;                                        \
            int row = f >> 7;                                                 \
            int c = ((f >> 3) & 15) ^ (row & 7);                              \
            gload16(Wt + (size_t)row * 768 + (kb) + c * 8, &Bs[bufi][f]);     \
        }                                                                     \
    } while (0)

    STB(0, 0);
#pragma unroll
    for (int kg = 0; kg < 2; kg++)
#pragma unroll
        for (int tm = 0; tm < 2; tm++)
            af[kg][tm] = *(const bf16x8*)(ga + tm * 12288 + kg * 32);
    __syncthreads();
#pragma unroll
    for (int ch = 0; ch < 6; ch++) {
        if (ch < 5) STB((ch + 1) & 1, (ch + 1) * 128);
#pragma unroll
        for (int k4 = 0; k4 < 4; k4++) {
            const int kg = ch * 4 + k4;
            if (kg + 2 < 24) {
#pragma unroll
                for (int tm = 0; tm < 2; tm++)
                    af[kg + 2][tm] = *(const bf16x8*)(ga + tm * 12288 + (kg + 2) * 32);
            }
            bf16x8 bfr[12];
#pragma unroll
            for (int tn = 0; tn < 12; tn++) {
                int row = tn * 16 + lc;
                int p = (k4 * 4 + lg) ^ (row & 7);
                bfr[tn] = *(const bf16x8*)&Bs[ch & 1][row * 128 + p * 8];
            }
#pragma unroll
            for (int tm = 0; tm < 2; tm++)
#pragma unroll
                for (int tn = 0; tn < 12; tn++)
                    acc[tm][tn] = __builtin_amdgcn_mfma_f32_16x16x32_bf16(af[kg][tm], bfr[tn],
                                                                         acc[tm][tn], 0, 0, 0);
        }
        __syncthreads();
    }
#undef STB
    float bv[12];
#pragma unroll
    for (int tn = 0; tn < 12; tn++) bv[tn] = bias[tn * 16 + lc];
    float gv[12], bb[12];
    if (DO_LN) {
#pragma unroll
        for (int tn = 0; tn < 12; tn++) { gv[tn] = g[tn * 16 + lc]; bb[tn] = b[tn * 16 + lc]; }
    }
#pragma unroll
    for (int tm = 0; tm < 2; tm++)
#pragma unroll
        for (int r = 0; r < 4; r++) {
            int row = w * 32 + tm * 16 + (lg << 2) + r;
            size_t base = (m0 + row) * 192;
            float v[12], s = 0.f;
#pragma unroll
            for (int tn = 0; tn < 12; tn++) {
                v[tn] = acc[tm][tn][r] + bv[tn] + res[base + tn * 16 + lc];
                s += v[tn];
            }
#pragma unroll
            for (int tn = 0; tn < 12; tn++) res[base + tn * 16 + lc] = v[tn];
            if (DO_LN) {
                s = redsum16(s);
                float mu = s * (1.f / 192.f);
                float q = 0.f;
#pragma unroll
                for (int tn = 0; tn < 12; tn++) { float d = v[tn] - mu; q += d * d; }
                q = redsum16(q);
                float rstd = rsqrtf(q * (1.f / 192.f) + 1e-5f);
#pragma unroll
                for (int tn = 0; tn < 12; tn++)
                    lnout[base + tn * 16 + lc] = f2bf((v[tn] - mu) * rstd * gv[tn] + bb[tn]);
            }
        }
}

// ---------------- windowed attention: 1 wave per (window, head) ----------------
__global__ __launch_bounds__(64) void attn_k(const u16* __restrict__ qkv,
                                             const float* __restrict__ rpb,
                                             u16* __restrict__ aout, int shifted) {
    __shared__ __align__(16) u16 Vt[32][72];
    __shared__ __align__(16) u16 Ps[64][72];
    const int l = threadIdx.x;
    const int head = blockIdx.x;
    const int wy = blockIdx.y;
    const int b = wy >> 10, widx = wy & 1023;
    const int wh = widx >> 5, ww = widx & 31;
    const int soff = shifted ? 4 : 0;
    const int lc = l & 15;
    const int lg = l >> 4;

    {
        int i1 = l >> 3, j1 = l & 7;
        int hh = (wh * 8 + i1 + soff) & 255;
        int wc = (ww * 8 + j1 + soff) & 255;
        const u16* base = qkv + (((size_t)b * 256 + hh) * 256 + wc) * 576 + head * 32 + 384;
#pragma unroll
        for (int s = 0; s < 4; s++) {
            u16x8 v = *(const u16x8*)(base + s * 8);
#pragma unroll
            for (int e = 0; e < 8; e++) Vt[s * 8 + e][l] = v[e];
        }
    }

    bf16x8 qa[4], kb[4];
#pragma unroll
    for (int tm = 0; tm < 4; tm++) {
        int p = tm * 16 + lc;
        int pi = p >> 3, pj = p & 7;
        int hh = (wh * 8 + pi + soff) & 255;
        int wc = (ww * 8 + pj + soff) & 255;
        const u16* tp = qkv + (((size_t)b * 256 + hh) * 256 + wc) * 576 + head * 32;
        qa[tm] = *(const bf16x8*)(tp + lg * 8);
        kb[tm] = *(const bf16x8*)(tp + 192 + lg * 8);
    }

    f32x4 acc[4][4] = {};
    __builtin_amdgcn_s_setprio(1);
#pragma unroll
    for (int tm = 0; tm < 4; tm++)
#pragma unroll
        for (int tn = 0; tn < 4; tn++)
            acc[tm][tn] = __builtin_amdgcn_mfma_f32_16x16x32_bf16(qa[tm], kb[tn], acc[tm][tn], 0, 0, 0);
    __builtin_amdgcn_s_setprio(0);

    const float scale = 0.17677669529663687f;
    const float* rp = rpb + head * 225;
#pragma unroll
    for (int tm = 0; tm < 4; tm++) {
#pragma unroll
        for (int r = 0; r < 4; r++) {
            int p = tm * 16 + (lg << 2) + r;
            int pi = p >> 3, pj = p & 7;
            float sv[4];
#pragma unroll
            for (int tn = 0; tn < 4; tn++) {
                int qq = tn * 16 + lc;
                int qi = qq >> 3, qj = qq & 7;
                float xv = acc[tm][tn][r] * scale + rp[(pi - qi + 7) * 15 + (pj - qj + 7)];
                if (shifted) {
                    bool msk = (wh == 31 && ((pi < 4) != (qi < 4))) ||
                               (ww == 31 && ((pj < 4) != (qj < 4)));
                    if (msk) xv = -1e30f;
                }
                sv[tn] = xv;
            }
            float mx = fmaxf(fmaxf(sv[0], sv[1]), fmaxf(sv[2], sv[3]));
#pragma unroll
            for (int m = 1; m < 16; m <<= 1) mx = fmaxf(mx, __shfl_xor(mx, m, 64));
            float sum = 0.f;
#pragma unroll
            for (int tn = 0; tn < 4; tn++) { sv[tn] = __expf(sv[tn] - mx); sum += sv[tn]; }
#pragma unroll
            for (int m = 1; m < 16; m <<= 1) sum += __shfl_xor(sum, m, 64);
            float inv = 1.0f / sum;
#pragma unroll
            for (int tn = 0; tn < 4; tn++) Ps[p][tn * 16 + lc] = f2bf(sv[tn] * inv);
        }
    }
    __syncthreads();

    f32x4 o[4][2] = {};
    {
        bf16x8 pa[4], vb[2];
#pragma unroll
        for (int kk = 0; kk < 2; kk++) {
#pragma unroll
            for (int tm = 0; tm < 4; tm++) pa[tm] = *(const bf16x8*)&Ps[tm * 16 + lc][kk * 32 + lg * 8];
#pragma unroll
            for (int tn = 0; tn < 2; tn++) vb[tn] = *(const bf16x8*)&Vt[tn * 16 + lc][kk * 32 + lg * 8];
            __builtin_amdgcn_s_setprio(1);
#pragma unroll
            for (int tm = 0; tm < 4; tm++)
#pragma unroll
                for (int tn = 0; tn < 2; tn++)
                    o[tm][tn] = __builtin_amdgcn_mfma_f32_16x16x32_bf16(pa[tm], vb[tn], o[tm][tn], 0, 0, 0);
            __builtin_amdgcn_s_setprio(0);
        }
    }
#pragma unroll
    for (int tm = 0; tm < 4; tm++)
#pragma unroll
        for (int r = 0; r < 4; r++) {
            int p = tm * 16 + (lg << 2) + r;
            int pi = p >> 3, pj = p & 7;
            int h2 = (wh * 8 + pi + soff) & 255;
            int w2 = (ww * 8 + pj + soff) & 255;
            size_t t2 = ((size_t)b * 256 + h2) * 256 + w2;
#pragma unroll
            for (int tn = 0; tn < 2; tn++)
                aout[t2 * 192 + head * 32 + tn * 16 + lc] = f2bf(o[tm][tn][r]);
        }
}

extern "C" void kernel_launch(void* const* d_in, const int* in_sizes, int n_in,
                              void* d_out, int out_size, void* d_ws, size_t ws_size,
                              hipStream_t stream) {
    (void)in_sizes; (void)n_in; (void)out_size; (void)ws_size;
    const float* x_in = (const float*)d_in[0];
    const size_t Ntok = (size_t)2 * 256 * 256;

    char* ws = (char*)d_ws;
    float* xbuf = (float*)ws;                       // 100,663,296 B
    u16* lnbuf = (u16*)(ws + 100663296);            //  50,331,648 B
    u16* big   = (u16*)(ws + 150994944);            // 201,326,592 B
    u16* wts   = (u16*)(ws + 352321536);

    u16* qkvt[2]; u16* projt[2]; u16* w1t[2]; u16* w2t[2];
    for (int bi = 0; bi < 2; bi++) {
        size_t base = (size_t)bi * 442368;
        qkvt[bi]  = wts + base;
        projt[bi] = wts + base + 110592;
        w1t[bi]   = wts + base + 147456;
        w2t[bi]   = wts + base + 294912;
    }

    transpose_in<<<dim3(2048, 6, 2), dim3(32, 8), 0, stream>>>(x_in, xbuf);

    for (int bi = 0; bi < 2; bi++) {
        const int base = 1 + bi * 13;
        wtrans<<<dim3((110592 + 255) / 256), 256, 0, stream>>>((const float*)d_in[base + 2],  qkvt[bi],  192, 576);
        wtrans<<<dim3((36864  + 255) / 256), 256, 0, stream>>>((const float*)d_in[base + 5],  projt[bi], 192, 192);
        wtrans<<<dim3((147456 + 255) / 256), 256, 0, stream>>>((const float*)d_in[base + 9],  w1t[bi],   192, 768);
        wtrans<<<dim3((147456 + 255) / 256), 256, 0, stream>>>((const float*)d_in[base + 11], w2t[bi],   768, 192);
    }

    // block-1 LN1 (the only standalone LN)
    ln_k<<<(int)(Ntok / 4), 256, 0, stream>>>(xbuf, (const float*)d_in[1], (const float*)d_in[2], lnbuf);

    for (int bi = 0; bi < 2; bi++) {
        const int base = 1 + bi * 13;
        const float* qkv_b  = (const float*)d_in[base + 3];
        const float* rpb    = (const float*)d_in[base + 4];
        const float* proj_b = (const float*)d_in[base + 6];
        const float* ln2_g  = (const float*)d_in[base + 7];
        const float* ln2_b  = (const float*)d_in[base + 8];
        const float* b1     = (const float*)d_in[base + 10];
        const float* b2     = (const float*)d_in[base + 12];

        // QKV GEMM: lnbuf -> big
        gemm_small<0><<<9216, 256, 0, stream>>>(lnbuf, qkvt[bi], qkv_b, big, 576, 9);
        // attention: big -> lnbuf
        attn_k<<<dim3(6, 2048), 64, 0, stream>>>(big, rpb, lnbuf, bi);
        // proj + residual + LN2: lnbuf(A) -> xbuf(res), lnbuf(ln out, in place rows)
        proj_ln_k<<<1024, 256, 0, stream>>>(lnbuf, projt[bi], proj_b, xbuf, ln2_g, ln2_b, lnbuf);
        // MLP1 + GELU: lnbuf -> big
        gemm_small<1><<<12288, 256, 0, stream>>>(lnbuf, w1t[bi], b1, big, 768, 12);
        // MLP2 + residual (+ fused LN1 of next block)
        if (bi == 0) {
            mlp2_k<1><<<512, 512, 0, stream>>>(big, w2t[bi], b2, xbuf,
                                               (const float*)d_in[14], (const float*)d_in[15], lnbuf);
        } else {
            mlp2_k<0><<<512, 512, 0, stream>>>(big, w2t[bi], b2, xbuf, nullptr, nullptr, nullptr);
        }
    }

    transpose_out<<<dim3(2048, 6, 2), dim3(32, 8), 0, stream>>>(xbuf, (float*)d_out);
}